// Round 13
// baseline (876.059 us; speedup 1.0000x reference)
//
#include <hip/hip_runtime.h>
#include <math.h>

#define Hn   256
#define En   128
#define Vn   256
#define TPn  32
#define BTn  2048
#define NSV  8              // seqs per WG
#define NWG  (BTn / NSV)    // 256 workgroups
#define NT   1024           // 16 waves
#define SROW2 258           // scx row stride (floats)

#define KATTR __attribute__((amdgpu_flat_work_group_size(1024, 1024), amdgpu_waves_per_eu(4, 4)))

typedef __attribute__((ext_vector_type(8))) short bf16x8;   // 8 bf16 = 4 VGPR
typedef __attribute__((ext_vector_type(4))) float f32x4;
typedef __attribute__((ext_vector_type(2))) float f32x2;    // legal for nontemporal

__device__ __forceinline__ float sigf(float x) {
    return __builtin_amdgcn_rcpf(1.0f + __expf(-x));
}
__device__ __forceinline__ float tanh_fast(float x) {
    float e = __expf(2.0f * x);
    return 1.0f - 2.0f * __builtin_amdgcn_rcpf(e + 1.0f);
}
__device__ __forceinline__ unsigned bf16rne(float x) {
    unsigned b = __float_as_uint(x);
    return (b + 0x7FFFu + ((b >> 16) & 1u)) >> 16;
}
__device__ __forceinline__ unsigned pk2(float a, float b) {
    return bf16rne(a) | (bf16rne(b) << 16);
}
__device__ __forceinline__ float bfu(unsigned short x) {
    return __uint_as_float(((unsigned)x) << 16);
}
__device__ __forceinline__ unsigned long long amax_key(float sc, int v) {
    unsigned fb = __float_as_uint(sc);
    fb = (fb & 0x80000000u) ? ~fb : (fb | 0x80000000u);   // order-preserving
    return ((unsigned long long)fb << 32) | (unsigned)(Vn - 1 - v);  // first-idx tie
}
__device__ __forceinline__ float dot4(float4 a, float4 b, float acc) {
    return fmaf(a.x, b.x, fmaf(a.y, b.y, fmaf(a.z, b.z, fmaf(a.w, b.w, acc))));
}

// ---------------- precompute kernels ----------------

__global__ void make_ptab(float4* __restrict__ Pp, const float* __restrict__ emb,
                          const float* __restrict__ Wih, const float* __restrict__ bih,
                          const float* __restrict__ bhh) {
    int v = blockIdx.x, u = threadIdx.x;
    __shared__ __align__(16) float es[En];
    if (u < En) es[u] = emb[v * En + u];
    __syncthreads();
    float a[4];
#pragma unroll
    for (int g = 0; g < 4; ++g) {
        int r = g * Hn + u;
        float acc = bih[r] + bhh[r];
        const float4* w4 = (const float4*)(Wih + r * En);
        const float4* e4 = (const float4*)es;
        for (int k = 0; k < En / 4; ++k) acc = dot4(w4[k], e4[k], acc);
        a[g] = acc;
    }
    Pp[v * Hn + u] = make_float4(a[0], a[1], a[2], a[3]);
}

// A-fragment pack for mfma_f32_16x16x32_bf16 (Wcat rows: 1024 gates [+ 256 fc]).
__global__ void pack_afrag(uint4* __restrict__ A, const float* __restrict__ Whh,
                           const float* __restrict__ fcW, int ntile) {
    int idx = blockIdx.x * 256 + threadIdx.x;
    if (idx >= ntile * 512) return;
    int l = idx & 63, q = (idx >> 6) & 7, t = idx >> 9;
    int r = 16 * t + (l & 15);
    int kb = 32 * q + 8 * (l >> 4);
    const float* s = (r < 1024) ? (Whh + r * Hn + kb) : (fcW + (r - 1024) * Hn + kb);
    A[idx] = make_uint4(pk2(s[0], s[1]), pk2(s[2], s[3]), pk2(s[4], s[5]), pk2(s[6], s[7]));
}

// ---------------- encoder ----------------
// Wave owns 4 M-tiles; tile 0 FULLY resident in LDS (128 KB); gate-gact bf16.
__global__ KATTR void enc_kernel(
    const bf16x8* __restrict__ AW, const float4* __restrict__ Ptu,
    const int* __restrict__ phon, const int* __restrict__ lens,
    float* __restrict__ h0dec) {
    const int tid = threadIdx.x, wg = blockIdx.x;
    const int wv = tid >> 6, l = tid & 63;
    const int c16 = l & 15, rg = l >> 4;
    const int u = tid >> 2, ch = tid & 3;
    const int sA = 2 * ch, sB = 2 * ch + 1;
    __shared__ __align__(16) bf16x8 resW[128 * 64];           // 131,072 B
    __shared__ __align__(16) uint4 hBf[8 * 64];               // 8,192 B
    __shared__ unsigned short gactG[1024 * 8];                // 16,384 B
    __shared__ int lsh[NSV];                                  // -> ~155.7 KB

    if (tid < 512) hBf[tid] = make_uint4(0u, 0u, 0u, 0u);   // h0 = 0
    if (tid < NSV) lsh[tid] = lens[wg * NSV + tid];
#pragma unroll
    for (int q = 0; q < 8; ++q)   // full tile 0 resident, wave-private
        resW[(wv * 8 + q) * 64 + l] = AW[((4 * wv) * 8 + q) * 64 + l];
    float cA = 0.f, cB = 0.f;
    __syncthreads();
    int mx = 0;
#pragma unroll
    for (int i = 0; i < NSV; ++i) mx = max(mx, lsh[i]);
    const int lenA = lsh[sA], lenB = lsh[sB];

    const bf16x8* AWw = AW + (4 * wv) * 512 + l;

    for (int t = 0; t < mx; ++t) {
        const int tokA = phon[(wg * NSV + sA) * TPn + t];
        const int tokB = phon[(wg * NSV + sB) * TPn + t];

        f32x4 acc[4];
#pragma unroll
        for (int ii = 0; ii < 4; ++ii) acc[ii] = (f32x4){0.f, 0.f, 0.f, 0.f};
#pragma unroll
        for (int q = 0; q < 8; ++q) {
            bf16x8 bf = *(const bf16x8*)&hBf[q * 64 + l];
            acc[0] = __builtin_amdgcn_mfma_f32_16x16x32_bf16(
                resW[(wv * 8 + q) * 64 + l], bf, acc[0], 0, 0, 0);
#pragma unroll
            for (int ii = 1; ii < 4; ++ii) {
                acc[ii] = __builtin_amdgcn_mfma_f32_16x16x32_bf16(
                    AWw[ii * 512 + q * 64], bf, acc[ii], 0, 0, 0);
            }
        }
        const float4 pA = Ptu[tokA * Hn + u];   // in flight during C-write
        const float4 pB = Ptu[tokB * Hn + u];
        if (c16 < 8) {   // C: col=lane&15 (seq), row=(lane>>4)*4+reg [m89-verified]
#pragma unroll
            for (int ii = 0; ii < 4; ++ii) {
                int Rb = (4 * wv + ii) * 16 + rg * 4;
#pragma unroll
                for (int r = 0; r < 4; ++r)
                    gactG[(Rb + r) * 8 + c16] = (unsigned short)bf16rne(acc[ii][r]);
            }
        }
        __syncthreads();   // bar1: gactG visible; hBf reads done

        float g0A = bfu(gactG[(u) * 8 + sA]),         g0B = bfu(gactG[(u) * 8 + sB]);
        float g1A = bfu(gactG[(256 + u) * 8 + sA]),   g1B = bfu(gactG[(256 + u) * 8 + sB]);
        float g2A = bfu(gactG[(512 + u) * 8 + sA]),   g2B = bfu(gactG[(512 + u) * 8 + sB]);
        float g3A = bfu(gactG[(768 + u) * 8 + sA]),   g3B = bfu(gactG[(768 + u) * 8 + sB]);
        float hvA, hvB;
        {
            float gi = sigf(g0A + pA.x), gf = sigf(g1A + pA.y);
            float gg = tanh_fast(g2A + pA.z), go = sigf(g3A + pA.w);
            cA = fmaf(gf, cA, gi * gg); hvA = go * tanh_fast(cA);
        }
        {
            float gi = sigf(g0B + pB.x), gf = sigf(g1B + pB.y);
            float gg = tanh_fast(g2B + pB.z), go = sigf(g3B + pB.w);
            cB = fmaf(gf, cB, gi * gg); hvB = go * tanh_fast(cB);
        }
        if (t == lenA - 1) __builtin_nontemporal_store(hvA, &h0dec[(wg * NSV + sA) * Hn + u]);
        if (t == lenB - 1) __builtin_nontemporal_store(hvB, &h0dec[(wg * NSV + sB) * Hn + u]);
        {   // new h into B-fragment layout (k=u -> q=u>>5, g=(u>>3)&3, j=u&7)
            unsigned short* hb16 = (unsigned short*)hBf;
            int q = u >> 5, g = (u >> 3) & 3, j = u & 7;
            hb16[(q * 64 + g * 16 + sA) * 8 + j] = (unsigned short)bf16rne(hvA);
            hb16[(q * 64 + g * 16 + sB) * 8 + j] = (unsigned short)bf16rne(hvB);
        }
        __syncthreads();   // bar2: new h fragments visible
    }
}

// ---------------- decoder ----------------
// Wave owns 5 M-tiles (1024 gates + 256 fc). Tile 0 resident (127/128 chunks).
// fc scores/argmax in-register by waves 12-15 pre-bar1 (bias in MFMA C-init);
// 2 barriers/iter. Gate-gact bf16; scx kept only as coalesced-out staging.
__global__ KATTR void dec_kernel(
    const bf16x8* __restrict__ AW, const float4* __restrict__ Ptu,
    const float* __restrict__ fcb, const float* __restrict__ h0dec,
    const int* __restrict__ sosp, float* __restrict__ out) {
    const int tid = threadIdx.x, wg = blockIdx.x;
    const int wv = tid >> 6, l = tid & 63;
    const int c16 = l & 15, rg = l >> 4;
    const int u = tid >> 2, ch = tid & 3;
    const int sA = 2 * ch, sB = 2 * ch + 1;
    __shared__ __align__(16) bf16x8 resW[127 * 64];           // 130,048 B
    __shared__ __align__(16) uint4 hBf[8 * 64];               // 8,192 B
    __shared__ unsigned short gactG[1024 * 8];                // 16,384 B
    __shared__ float scx[NSV * SROW2];                        // 8,256 B
    __shared__ unsigned long long gmax[2][NSV];               // 128 B -> ~163.0 KB

    if (tid < 512) {   // stage h0 into B-fragment layout
        int q = tid >> 6, ll = tid & 63, c = ll & 15, g = ll >> 4;
        uint4 v = make_uint4(0u, 0u, 0u, 0u);
        if (c < 8) {
            const float* hp = h0dec + (wg * NSV + c) * Hn + 32 * q + 8 * g;
            float4 v0 = *(const float4*)hp;
            float4 v1 = *(const float4*)(hp + 4);
            v = make_uint4(pk2(v0.x, v0.y), pk2(v0.z, v0.w), pk2(v1.x, v1.y), pk2(v1.z, v1.w));
        }
        hBf[tid] = v;
    }
    if (tid < 2 * NSV) ((unsigned long long*)gmax)[tid] = 0ull;
#pragma unroll
    for (int q = 0; q < 8; ++q)   // tile 0 resident (all but wave15 q7)
        if (wv < 15 || q < 7)
            resW[(wv * 8 + q) * 64 + l] = AW[((5 * wv) * 8 + q) * 64 + l];
    const int sos0 = sosp[0];
    float cA = 0.f, cB = 0.f;
    __syncthreads();

    const bf16x8* AWw = AW + (5 * wv) * 512 + l;

    for (int i = 0; i <= TPn; ++i) {
        const bool full = (i < TPn);

        f32x4 acc[5];
#pragma unroll
        for (int ii = 0; ii < 5; ++ii) {
            const int t5 = 5 * wv + ii;
            if (t5 >= 64) {   // fc tile: bias folded into MFMA C-init (loop-inv L2-hot load)
                acc[ii] = *(const f32x4*)&fcb[(t5 - 64) * 16 + rg * 4];
            } else {
                acc[ii] = (f32x4){0.f, 0.f, 0.f, 0.f};
            }
        }
#pragma unroll
        for (int q = 0; q < 8; ++q) {
            bf16x8 bf = *(const bf16x8*)&hBf[q * 64 + l];
            bf16x8 a0 = (wv < 15 || q < 7) ? resW[(wv * 8 + q) * 64 + l] : AWw[q * 64];
            acc[0] = __builtin_amdgcn_mfma_f32_16x16x32_bf16(a0, bf, acc[0], 0, 0, 0);
#pragma unroll
            for (int ii = 1; ii < 5; ++ii) {
                acc[ii] = __builtin_amdgcn_mfma_f32_16x16x32_bf16(
                    AWw[ii * 512 + q * 64], bf, acc[ii], 0, 0, 0);
            }
        }
        // gate tiles -> gactG (bf16)
        if (c16 < 8) {
#pragma unroll
            for (int ii = 0; ii < 5; ++ii) {
                const int t5 = 5 * wv + ii;
                if (t5 < 64) {
                    int Rb = t5 * 16 + rg * 4;
#pragma unroll
                    for (int r = 0; r < 4; ++r)
                        gactG[(Rb + r) * 8 + c16] = (unsigned short)bf16rne(acc[ii][r]);
                }
            }
        }
        // fc tiles -> scores (scx for out-staging) + in-register argmax, pre-bar1
        if (i > 0) {
            unsigned long long kbest = 0ull;
            if (c16 < 8) {
#pragma unroll
                for (int ii = 0; ii < 5; ++ii) {
                    const int t5 = 5 * wv + ii;
                    if (t5 >= 64) {
                        int vb = (t5 - 64) * 16 + rg * 4;
#pragma unroll
                        for (int r = 0; r < 4; ++r) {
                            float sc = acc[ii][r];          // bias already included
                            scx[c16 * SROW2 + vb + r] = sc;
                            unsigned long long k = amax_key(sc, vb + r);
                            if (k > kbest) kbest = k;
                        }
                    }
                }
            }
            if (wv >= 12) {   // butterfly over rg lanes (bits 4,5), then publish
                unsigned long long o = __shfl_xor(kbest, 16, 64); if (o > kbest) kbest = o;
                o = __shfl_xor(kbest, 32, 64); if (o > kbest) kbest = o;
                if (c16 < 8 && rg == 0) atomicMax(&gmax[i & 1][c16], kbest);
            }
        }
        __syncthreads();   // bar1: gactG + scx + gmax visible; hBf reads done

        int tokA = sos0, tokB = sos0;
        if (i > 0) {
            {   // coalesced nt store of scores_{i-1}
                int s = tid >> 7, k = (tid & 127) * 2;
                f32x2 v = *(const f32x2*)&scx[s * SROW2 + k];
                __builtin_nontemporal_store(
                    v, (f32x2*)&out[((long)(wg * NSV + s) * TPn + (i - 1)) * Vn + k]);
            }
            tokA = (Vn - 1) - (int)(gmax[i & 1][sA] & 0xffffffffu);
            tokB = (Vn - 1) - (int)(gmax[i & 1][sB] & 0xffffffffu);
            if (tid < NSV) gmax[(i + 1) & 1][tid] = 0ull;   // reset other parity slot
        }

        if (full) {
            const float4 pA = Ptu[tokA * Hn + u];
            const float4 pB = Ptu[tokB * Hn + u];
            float g0A = bfu(gactG[(u) * 8 + sA]),       g0B = bfu(gactG[(u) * 8 + sB]);
            float g1A = bfu(gactG[(256 + u) * 8 + sA]), g1B = bfu(gactG[(256 + u) * 8 + sB]);
            float g2A = bfu(gactG[(512 + u) * 8 + sA]), g2B = bfu(gactG[(512 + u) * 8 + sB]);
            float g3A = bfu(gactG[(768 + u) * 8 + sA]), g3B = bfu(gactG[(768 + u) * 8 + sB]);
            float hvA, hvB;
            {
                float gi = sigf(g0A + pA.x), gf = sigf(g1A + pA.y);
                float gg = tanh_fast(g2A + pA.z), go = sigf(g3A + pA.w);
                cA = fmaf(gf, cA, gi * gg); hvA = go * tanh_fast(cA);
            }
            {
                float gi = sigf(g0B + pB.x), gf = sigf(g1B + pB.y);
                float gg = tanh_fast(g2B + pB.z), go = sigf(g3B + pB.w);
                cB = fmaf(gf, cB, gi * gg); hvB = go * tanh_fast(cB);
            }
            unsigned short* hb16 = (unsigned short*)hBf;
            int q = u >> 5, g = (u >> 3) & 3, j = u & 7;
            hb16[(q * 64 + g * 16 + sA) * 8 + j] = (unsigned short)bf16rne(hvA);
            hb16[(q * 64 + g * 16 + sB) * 8 + j] = (unsigned short)bf16rne(hvB);
        }
        __syncthreads();   // bar2: new h + gmax reset visible
    }
}

// ---------------- launch ----------------
extern "C" void kernel_launch(void* const* d_in, const int* in_sizes, int n_in,
                              void* d_out, int out_size, void* d_ws, size_t ws_size,
                              hipStream_t stream) {
    const int*   phon = (const int*)d_in[0];
    const int*   lens = (const int*)d_in[1];
    const float* emb  = (const float*)d_in[2];
    const float* eWih = (const float*)d_in[3];
    const float* eWhh = (const float*)d_in[4];
    const float* ebih = (const float*)d_in[5];
    const float* ebhh = (const float*)d_in[6];
    const float* dWih = (const float*)d_in[7];
    const float* dWhh = (const float*)d_in[8];
    const float* dbih = (const float*)d_in[9];
    const float* dbhh = (const float*)d_in[10];
    const float* fcW  = (const float*)d_in[11];
    const float* fcb  = (const float*)d_in[12];
    const int*   sos  = (const int*)d_in[13];
    float* out = (float*)d_out;

    float4* Ptu_e = (float4*)d_ws;            // 1 MB
    float4* Ptu_d = Ptu_e + 65536;            // 1 MB
    uint4*  AW_e  = (uint4*)(Ptu_d + 65536);  // 512 KB
    uint4*  AW_d  = AW_e + 32768;             // 640 KB
    float*  h0d   = (float*)(AW_d + 40960);   // 2 MB

    make_ptab<<<256, 256, 0, stream>>>(Ptu_e, emb, eWih, ebih, ebhh);
    make_ptab<<<256, 256, 0, stream>>>(Ptu_d, emb, dWih, dbih, dbhh);
    pack_afrag<<<128, 256, 0, stream>>>(AW_e, eWhh, eWhh, 64);   // fcW unused (ntile=64)
    pack_afrag<<<160, 256, 0, stream>>>(AW_d, dWhh, fcW, 80);
    enc_kernel<<<NWG, NT, 0, stream>>>((const bf16x8*)AW_e, Ptu_e, phon, lens, h0d);
    dec_kernel<<<NWG, NT, 0, stream>>>((const bf16x8*)AW_d, Ptu_d, fcb, h0d, sos, out);
}

// Round 14
// 863.194 us; speedup vs baseline: 1.0149x; 1.0149x over previous
//
#include <hip/hip_runtime.h>
#include <math.h>

#define Hn   256
#define En   128
#define Vn   256
#define TPn  32
#define BTn  2048
#define NSV  8              // seqs per WG
#define NWG  (BTn / NSV)    // 256 workgroups
#define NT   1024           // 16 waves
#define SROW2 258           // scx row stride (floats)
#define RESQ_D 7            // dec: resident q-chunks of each wave's tile 0 (of 8)

#define KATTR __attribute__((amdgpu_flat_work_group_size(1024, 1024), amdgpu_waves_per_eu(4, 4)))

typedef __attribute__((ext_vector_type(8))) short bf16x8;   // 8 bf16 = 4 VGPR
typedef __attribute__((ext_vector_type(4))) float f32x4;
typedef __attribute__((ext_vector_type(2))) float f32x2;    // legal for nontemporal

__device__ __forceinline__ float sigf(float x) {
    return __builtin_amdgcn_rcpf(1.0f + __expf(-x));
}
__device__ __forceinline__ float tanh_fast(float x) {
    float e = __expf(2.0f * x);
    return 1.0f - 2.0f * __builtin_amdgcn_rcpf(e + 1.0f);
}
__device__ __forceinline__ unsigned bf16rne(float x) {
    unsigned b = __float_as_uint(x);
    return (b + 0x7FFFu + ((b >> 16) & 1u)) >> 16;
}
__device__ __forceinline__ unsigned pk2(float a, float b) {
    return bf16rne(a) | (bf16rne(b) << 16);
}
__device__ __forceinline__ float bfu(unsigned short x) {
    return __uint_as_float(((unsigned)x) << 16);
}
__device__ __forceinline__ unsigned long long amax_key(float sc, int v) {
    unsigned fb = __float_as_uint(sc);
    fb = (fb & 0x80000000u) ? ~fb : (fb | 0x80000000u);   // order-preserving
    return ((unsigned long long)fb << 32) | (unsigned)(Vn - 1 - v);  // first-idx tie
}
__device__ __forceinline__ float dot4(float4 a, float4 b, float acc) {
    return fmaf(a.x, b.x, fmaf(a.y, b.y, fmaf(a.z, b.z, fmaf(a.w, b.w, acc))));
}

// ---------------- precompute kernels ----------------

__global__ void make_ptab(float4* __restrict__ Pp, const float* __restrict__ emb,
                          const float* __restrict__ Wih, const float* __restrict__ bih,
                          const float* __restrict__ bhh) {
    int v = blockIdx.x, u = threadIdx.x;
    __shared__ __align__(16) float es[En];
    if (u < En) es[u] = emb[v * En + u];
    __syncthreads();
    float a[4];
#pragma unroll
    for (int g = 0; g < 4; ++g) {
        int r = g * Hn + u;
        float acc = bih[r] + bhh[r];
        const float4* w4 = (const float4*)(Wih + r * En);
        const float4* e4 = (const float4*)es;
        for (int k = 0; k < En / 4; ++k) acc = dot4(w4[k], e4[k], acc);
        a[g] = acc;
    }
    Pp[v * Hn + u] = make_float4(a[0], a[1], a[2], a[3]);
}

// A-fragment pack for mfma_f32_16x16x32_bf16 (Wcat rows: 1024 gates [+ 256 fc]).
__global__ void pack_afrag(uint4* __restrict__ A, const float* __restrict__ Whh,
                           const float* __restrict__ fcW, int ntile) {
    int idx = blockIdx.x * 256 + threadIdx.x;
    if (idx >= ntile * 512) return;
    int l = idx & 63, q = (idx >> 6) & 7, t = idx >> 9;
    int r = 16 * t + (l & 15);
    int kb = 32 * q + 8 * (l >> 4);
    const float* s = (r < 1024) ? (Whh + r * Hn + kb) : (fcW + (r - 1024) * Hn + kb);
    A[idx] = make_uint4(pk2(s[0], s[1]), pk2(s[2], s[3]), pk2(s[4], s[5]), pk2(s[6], s[7]));
}

// ---------------- encoder (R13 verbatim -- proven neutral/positive) ----------------
// Wave owns 4 M-tiles; tile 0 FULLY resident in LDS (128 KB); gate-gact bf16.
__global__ KATTR void enc_kernel(
    const bf16x8* __restrict__ AW, const float4* __restrict__ Ptu,
    const int* __restrict__ phon, const int* __restrict__ lens,
    float* __restrict__ h0dec) {
    const int tid = threadIdx.x, wg = blockIdx.x;
    const int wv = tid >> 6, l = tid & 63;
    const int c16 = l & 15, rg = l >> 4;
    const int u = tid >> 2, ch = tid & 3;
    const int sA = 2 * ch, sB = 2 * ch + 1;
    __shared__ __align__(16) bf16x8 resW[128 * 64];           // 131,072 B
    __shared__ __align__(16) uint4 hBf[8 * 64];               // 8,192 B
    __shared__ unsigned short gactG[1024 * 8];                // 16,384 B
    __shared__ int lsh[NSV];                                  // -> ~155.7 KB

    if (tid < 512) hBf[tid] = make_uint4(0u, 0u, 0u, 0u);   // h0 = 0
    if (tid < NSV) lsh[tid] = lens[wg * NSV + tid];
#pragma unroll
    for (int q = 0; q < 8; ++q)   // full tile 0 resident, wave-private
        resW[(wv * 8 + q) * 64 + l] = AW[((4 * wv) * 8 + q) * 64 + l];
    float cA = 0.f, cB = 0.f;
    __syncthreads();
    int mx = 0;
#pragma unroll
    for (int i = 0; i < NSV; ++i) mx = max(mx, lsh[i]);
    const int lenA = lsh[sA], lenB = lsh[sB];

    const bf16x8* AWw = AW + (4 * wv) * 512 + l;

    for (int t = 0; t < mx; ++t) {
        const int tokA = phon[(wg * NSV + sA) * TPn + t];
        const int tokB = phon[(wg * NSV + sB) * TPn + t];

        f32x4 acc[4];
#pragma unroll
        for (int ii = 0; ii < 4; ++ii) acc[ii] = (f32x4){0.f, 0.f, 0.f, 0.f};
#pragma unroll
        for (int q = 0; q < 8; ++q) {
            bf16x8 bf = *(const bf16x8*)&hBf[q * 64 + l];
            acc[0] = __builtin_amdgcn_mfma_f32_16x16x32_bf16(
                resW[(wv * 8 + q) * 64 + l], bf, acc[0], 0, 0, 0);
#pragma unroll
            for (int ii = 1; ii < 4; ++ii) {
                acc[ii] = __builtin_amdgcn_mfma_f32_16x16x32_bf16(
                    AWw[ii * 512 + q * 64], bf, acc[ii], 0, 0, 0);
            }
        }
        const float4 pA = Ptu[tokA * Hn + u];   // in flight during C-write
        const float4 pB = Ptu[tokB * Hn + u];
        if (c16 < 8) {   // C: col=lane&15 (seq), row=(lane>>4)*4+reg [m89-verified]
#pragma unroll
            for (int ii = 0; ii < 4; ++ii) {
                int Rb = (4 * wv + ii) * 16 + rg * 4;
#pragma unroll
                for (int r = 0; r < 4; ++r)
                    gactG[(Rb + r) * 8 + c16] = (unsigned short)bf16rne(acc[ii][r]);
            }
        }
        __syncthreads();   // bar1: gactG visible; hBf reads done

        float g0A = bfu(gactG[(u) * 8 + sA]),         g0B = bfu(gactG[(u) * 8 + sB]);
        float g1A = bfu(gactG[(256 + u) * 8 + sA]),   g1B = bfu(gactG[(256 + u) * 8 + sB]);
        float g2A = bfu(gactG[(512 + u) * 8 + sA]),   g2B = bfu(gactG[(512 + u) * 8 + sB]);
        float g3A = bfu(gactG[(768 + u) * 8 + sA]),   g3B = bfu(gactG[(768 + u) * 8 + sB]);
        float hvA, hvB;
        {
            float gi = sigf(g0A + pA.x), gf = sigf(g1A + pA.y);
            float gg = tanh_fast(g2A + pA.z), go = sigf(g3A + pA.w);
            cA = fmaf(gf, cA, gi * gg); hvA = go * tanh_fast(cA);
        }
        {
            float gi = sigf(g0B + pB.x), gf = sigf(g1B + pB.y);
            float gg = tanh_fast(g2B + pB.z), go = sigf(g3B + pB.w);
            cB = fmaf(gf, cB, gi * gg); hvB = go * tanh_fast(cB);
        }
        if (t == lenA - 1) __builtin_nontemporal_store(hvA, &h0dec[(wg * NSV + sA) * Hn + u]);
        if (t == lenB - 1) __builtin_nontemporal_store(hvB, &h0dec[(wg * NSV + sB) * Hn + u]);
        {   // new h into B-fragment layout (k=u -> q=u>>5, g=(u>>3)&3, j=u&7)
            unsigned short* hb16 = (unsigned short*)hBf;
            int q = u >> 5, g = (u >> 3) & 3, j = u & 7;
            hb16[(q * 64 + g * 16 + sA) * 8 + j] = (unsigned short)bf16rne(hvA);
            hb16[(q * 64 + g * 16 + sB) * 8 + j] = (unsigned short)bf16rne(hvB);
        }
        __syncthreads();   // bar2: new h fragments visible
    }
}

// ---------------- decoder ----------------
// R12's proven 3-barrier structure + only the enc-exonerated upgrades:
// gate-gact bf16 (stride-8, conflict-free) funds uniform RESQ_D=7.
// fc scores f32 in gactF (bias added at read); argmax after bar1 (R12 flow).
__global__ KATTR void dec_kernel(
    const bf16x8* __restrict__ AW, const float4* __restrict__ Ptu,
    const float* __restrict__ fcb, const float* __restrict__ h0dec,
    const int* __restrict__ sosp, float* __restrict__ out) {
    const int tid = threadIdx.x, wg = blockIdx.x;
    const int wv = tid >> 6, l = tid & 63;
    const int c16 = l & 15, rg = l >> 4;
    const int u = tid >> 2, ch = tid & 3;
    const int sA = 2 * ch, sB = 2 * ch + 1;
    const int ln = tid & 63;
    __shared__ __align__(16) bf16x8 resW[16 * RESQ_D * 64];   // 114,688 B
    __shared__ __align__(16) uint4 hBf[8 * 64];               // 8,192 B
    __shared__ unsigned short gactG[1024 * 8];                // 16,384 B
    __shared__ float gactF[256 * 9];                          // 9,216 B
    __shared__ float scx[NSV * SROW2];                        // 8,256 B
    __shared__ unsigned long long gmax[2][NSV];               // 128 B -> 156,864 total

    if (tid < 512) {   // stage h0 into B-fragment layout
        int q = tid >> 6, ll = tid & 63, c = ll & 15, g = ll >> 4;
        uint4 v = make_uint4(0u, 0u, 0u, 0u);
        if (c < 8) {
            const float* hp = h0dec + (wg * NSV + c) * Hn + 32 * q + 8 * g;
            float4 v0 = *(const float4*)hp;
            float4 v1 = *(const float4*)(hp + 4);
            v = make_uint4(pk2(v0.x, v0.y), pk2(v0.z, v0.w), pk2(v1.x, v1.y), pk2(v1.z, v1.w));
        }
        hBf[tid] = v;
    }
    if (tid < 2 * NSV) ((unsigned long long*)gmax)[tid] = 0ull;
#pragma unroll
    for (int q = 0; q < RESQ_D; ++q)   // wave-private resident tile0 q<7
        resW[(wv * RESQ_D + q) * 64 + l] = AW[((5 * wv) * 8 + q) * 64 + l];
    const int sos0 = sosp[0];
    const float fb = fcb[u];
    float cA = 0.f, cB = 0.f;
    __syncthreads();

    const bf16x8* AWw = AW + (5 * wv) * 512 + l;

    for (int i = 0; i <= TPn; ++i) {
        const bool full = (i < TPn);

        f32x4 acc[5];
#pragma unroll
        for (int ii = 0; ii < 5; ++ii) acc[ii] = (f32x4){0.f, 0.f, 0.f, 0.f};
#pragma unroll
        for (int q = 0; q < 8; ++q) {
            bf16x8 bf = *(const bf16x8*)&hBf[q * 64 + l];
            bf16x8 a0 = (q < RESQ_D) ? resW[(wv * RESQ_D + q) * 64 + l] : AWw[q * 64];
            acc[0] = __builtin_amdgcn_mfma_f32_16x16x32_bf16(a0, bf, acc[0], 0, 0, 0);
#pragma unroll
            for (int ii = 1; ii < 5; ++ii) {
                acc[ii] = __builtin_amdgcn_mfma_f32_16x16x32_bf16(
                    AWw[ii * 512 + q * 64], bf, acc[ii], 0, 0, 0);
            }
        }
        if (c16 < 8) {   // gate rows -> bf16 gactG; fc rows -> f32 gactF
#pragma unroll
            for (int ii = 0; ii < 5; ++ii) {
                const int t5 = 5 * wv + ii;
                const int Rb = t5 * 16 + rg * 4;
                if (t5 < 64) {
#pragma unroll
                    for (int r = 0; r < 4; ++r)
                        gactG[(Rb + r) * 8 + c16] = (unsigned short)bf16rne(acc[ii][r]);
                } else {
#pragma unroll
                    for (int r = 0; r < 4; ++r)
                        gactF[(Rb - 1024 + r) * 9 + c16] = acc[ii][r];
                }
            }
        }
        __syncthreads();   // bar1: gactG/gactF visible; hBf reads done

        float g0A = 0.f, g1A = 0.f, g2A = 0.f, g3A = 0.f;
        float g0B = 0.f, g1B = 0.f, g2B = 0.f, g3B = 0.f;
        if (full) {
            g0A = bfu(gactG[(u) * 8 + sA]);       g0B = bfu(gactG[(u) * 8 + sB]);
            g1A = bfu(gactG[(256 + u) * 8 + sA]); g1B = bfu(gactG[(256 + u) * 8 + sB]);
            g2A = bfu(gactG[(512 + u) * 8 + sA]); g2B = bfu(gactG[(512 + u) * 8 + sB]);
            g3A = bfu(gactG[(768 + u) * 8 + sA]); g3B = bfu(gactG[(768 + u) * 8 + sB]);
        }
        if (i > 0) {   // scores_{i-1} for v=u, seqs sA,sB (R12 flow)
            float scA = gactF[u * 9 + sA] + fb;
            float scB = gactF[u * 9 + sB] + fb;
            scx[sA * SROW2 + u] = scA;
            scx[sB * SROW2 + u] = scB;
            unsigned long long kA = amax_key(scA, u);
            unsigned long long kB = amax_key(scB, u);
#pragma unroll
            for (int off = 4; off < 64; off <<= 1) {
                unsigned long long oA = __shfl_xor(kA, off, 64);
                unsigned long long oB = __shfl_xor(kB, off, 64);
                if (oA > kA) kA = oA;
                if (oB > kB) kB = oB;
            }
            if (ln < 4) {
                atomicMax(&gmax[i & 1][sA], kA);
                atomicMax(&gmax[i & 1][sB], kB);
            }
        }
        __syncthreads();   // bar2: scx + gmax visible; gact reads done

        int tokA = sos0, tokB = sos0;
        if (i > 0) {
            {   // coalesced nt store of scores_{i-1}
                int s = tid >> 7, k = (tid & 127) * 2;
                f32x2 v = *(const f32x2*)&scx[s * SROW2 + k];
                __builtin_nontemporal_store(
                    v, (f32x2*)&out[((long)(wg * NSV + s) * TPn + (i - 1)) * Vn + k]);
            }
            tokA = (Vn - 1) - (int)(gmax[i & 1][sA] & 0xffffffffu);
            tokB = (Vn - 1) - (int)(gmax[i & 1][sB] & 0xffffffffu);
            if (tid < NSV) gmax[(i + 1) & 1][tid] = 0ull;   // reset other parity slot
        }

        if (full) {
            const float4 pA = Ptu[tokA * Hn + u];
            const float4 pB = Ptu[tokB * Hn + u];
            float hvA, hvB;
            {
                float gi = sigf(g0A + pA.x), gf = sigf(g1A + pA.y);
                float gg = tanh_fast(g2A + pA.z), go = sigf(g3A + pA.w);
                cA = fmaf(gf, cA, gi * gg); hvA = go * tanh_fast(cA);
            }
            {
                float gi = sigf(g0B + pB.x), gf = sigf(g1B + pB.y);
                float gg = tanh_fast(g2B + pB.z), go = sigf(g3B + pB.w);
                cB = fmaf(gf, cB, gi * gg); hvB = go * tanh_fast(cB);
            }
            unsigned short* hb16 = (unsigned short*)hBf;
            int q = u >> 5, g = (u >> 3) & 3, j = u & 7;
            hb16[(q * 64 + g * 16 + sA) * 8 + j] = (unsigned short)bf16rne(hvA);
            hb16[(q * 64 + g * 16 + sB) * 8 + j] = (unsigned short)bf16rne(hvB);
        }
        __syncthreads();   // bar3: new h + gmax reset visible
    }
}

// ---------------- launch ----------------
extern "C" void kernel_launch(void* const* d_in, const int* in_sizes, int n_in,
                              void* d_out, int out_size, void* d_ws, size_t ws_size,
                              hipStream_t stream) {
    const int*   phon = (const int*)d_in[0];
    const int*   lens = (const int*)d_in[1];
    const float* emb  = (const float*)d_in[2];
    const float* eWih = (const float*)d_in[3];
    const float* eWhh = (const float*)d_in[4];
    const float* ebih = (const float*)d_in[5];
    const float* ebhh = (const float*)d_in[6];
    const float* dWih = (const float*)d_in[7];
    const float* dWhh = (const float*)d_in[8];
    const float* dbih = (const float*)d_in[9];
    const float* dbhh = (const float*)d_in[10];
    const float* fcW  = (const float*)d_in[11];
    const float* fcb  = (const float*)d_in[12];
    const int*   sos  = (const int*)d_in[13];
    float* out = (float*)d_out;

    float4* Ptu_e = (float4*)d_ws;            // 1 MB
    float4* Ptu_d = Ptu_e + 65536;            // 1 MB
    uint4*  AW_e  = (uint4*)(Ptu_d + 65536);  // 512 KB
    uint4*  AW_d  = AW_e + 32768;             // 640 KB
    float*  h0d   = (float*)(AW_d + 40960);   // 2 MB

    make_ptab<<<256, 256, 0, stream>>>(Ptu_e, emb, eWih, ebih, ebhh);
    make_ptab<<<256, 256, 0, stream>>>(Ptu_d, emb, dWih, dbih, dbhh);
    pack_afrag<<<128, 256, 0, stream>>>(AW_e, eWhh, eWhh, 64);   // fcW unused (ntile=64)
    pack_afrag<<<160, 256, 0, stream>>>(AW_d, dWhh, fcW, 80);
    enc_kernel<<<NWG, NT, 0, stream>>>((const bf16x8*)AW_e, Ptu_e, phon, lens, h0d);
    dec_kernel<<<NWG, NT, 0, stream>>>((const bf16x8*)AW_d, Ptu_d, fcb, h0d, sos, out);
}

// Round 15
// 729.716 us; speedup vs baseline: 1.2005x; 1.1829x over previous
//
#include <hip/hip_runtime.h>
#include <math.h>

#define Hn   256
#define En   128
#define Vn   256
#define TPn  32
#define BTn  2048
#define NSV  8              // seqs per WG
#define NWG  (BTn / NSV)    // 256 workgroups
#define NT   1024           // 16 waves
#define SROW 260            // scx row stride (floats) -- dec (R12)
#define GSTR 9              // dec gact row stride (floats): 8 seqs + 1 pad (R12)
#define RESQ_D 6            // dec: resident q-chunks of each wave's tile 0 (R12-proven)

#define KATTR __attribute__((amdgpu_flat_work_group_size(1024, 1024), amdgpu_waves_per_eu(4, 4)))

typedef __attribute__((ext_vector_type(8))) short bf16x8;   // 8 bf16 = 4 VGPR
typedef __attribute__((ext_vector_type(4))) float f32x4;
typedef __attribute__((ext_vector_type(2))) float f32x2;    // legal for nontemporal

__device__ __forceinline__ float sigf(float x) {
    return __builtin_amdgcn_rcpf(1.0f + __expf(-x));
}
__device__ __forceinline__ float tanh_fast(float x) {
    float e = __expf(2.0f * x);
    return 1.0f - 2.0f * __builtin_amdgcn_rcpf(e + 1.0f);
}
__device__ __forceinline__ unsigned bf16rne(float x) {
    unsigned b = __float_as_uint(x);
    return (b + 0x7FFFu + ((b >> 16) & 1u)) >> 16;
}
__device__ __forceinline__ unsigned pk2(float a, float b) {
    return bf16rne(a) | (bf16rne(b) << 16);
}
__device__ __forceinline__ float bfu(unsigned short x) {
    return __uint_as_float(((unsigned)x) << 16);
}
__device__ __forceinline__ unsigned long long amax_key(float sc, int v) {
    unsigned fb = __float_as_uint(sc);
    fb = (fb & 0x80000000u) ? ~fb : (fb | 0x80000000u);   // order-preserving
    return ((unsigned long long)fb << 32) | (unsigned)(Vn - 1 - v);  // first-idx tie
}
__device__ __forceinline__ float dot4(float4 a, float4 b, float acc) {
    return fmaf(a.x, b.x, fmaf(a.y, b.y, fmaf(a.z, b.z, fmaf(a.w, b.w, acc))));
}

// ---------------- precompute kernels ----------------

__global__ void make_ptab(float4* __restrict__ Pp, const float* __restrict__ emb,
                          const float* __restrict__ Wih, const float* __restrict__ bih,
                          const float* __restrict__ bhh) {
    int v = blockIdx.x, u = threadIdx.x;
    __shared__ __align__(16) float es[En];
    if (u < En) es[u] = emb[v * En + u];
    __syncthreads();
    float a[4];
#pragma unroll
    for (int g = 0; g < 4; ++g) {
        int r = g * Hn + u;
        float acc = bih[r] + bhh[r];
        const float4* w4 = (const float4*)(Wih + r * En);
        const float4* e4 = (const float4*)es;
        for (int k = 0; k < En / 4; ++k) acc = dot4(w4[k], e4[k], acc);
        a[g] = acc;
    }
    Pp[v * Hn + u] = make_float4(a[0], a[1], a[2], a[3]);
}

// A-fragment pack for mfma_f32_16x16x32_bf16 (Wcat rows: 1024 gates [+ 256 fc]).
__global__ void pack_afrag(uint4* __restrict__ A, const float* __restrict__ Whh,
                           const float* __restrict__ fcW, int ntile) {
    int idx = blockIdx.x * 256 + threadIdx.x;
    if (idx >= ntile * 512) return;
    int l = idx & 63, q = (idx >> 6) & 7, t = idx >> 9;
    int r = 16 * t + (l & 15);
    int kb = 32 * q + 8 * (l >> 4);
    const float* s = (r < 1024) ? (Whh + r * Hn + kb) : (fcW + (r - 1024) * Hn + kb);
    A[idx] = make_uint4(pk2(s[0], s[1]), pk2(s[2], s[3]), pk2(s[4], s[5]), pk2(s[6], s[7]));
}

// ---------------- encoder (R13 verbatim -- measured neutral/positive) ----------------
// Wave owns 4 M-tiles; tile 0 FULLY resident in LDS (128 KB); gate-gact bf16.
__global__ KATTR void enc_kernel(
    const bf16x8* __restrict__ AW, const float4* __restrict__ Ptu,
    const int* __restrict__ phon, const int* __restrict__ lens,
    float* __restrict__ h0dec) {
    const int tid = threadIdx.x, wg = blockIdx.x;
    const int wv = tid >> 6, l = tid & 63;
    const int c16 = l & 15, rg = l >> 4;
    const int u = tid >> 2, ch = tid & 3;
    const int sA = 2 * ch, sB = 2 * ch + 1;
    __shared__ __align__(16) bf16x8 resW[128 * 64];           // 131,072 B
    __shared__ __align__(16) uint4 hBf[8 * 64];               // 8,192 B
    __shared__ unsigned short gactG[1024 * 8];                // 16,384 B
    __shared__ int lsh[NSV];                                  // -> ~155.7 KB

    if (tid < 512) hBf[tid] = make_uint4(0u, 0u, 0u, 0u);   // h0 = 0
    if (tid < NSV) lsh[tid] = lens[wg * NSV + tid];
#pragma unroll
    for (int q = 0; q < 8; ++q)   // full tile 0 resident, wave-private
        resW[(wv * 8 + q) * 64 + l] = AW[((4 * wv) * 8 + q) * 64 + l];
    float cA = 0.f, cB = 0.f;
    __syncthreads();
    int mx = 0;
#pragma unroll
    for (int i = 0; i < NSV; ++i) mx = max(mx, lsh[i]);
    const int lenA = lsh[sA], lenB = lsh[sB];

    const bf16x8* AWw = AW + (4 * wv) * 512 + l;

    for (int t = 0; t < mx; ++t) {
        const int tokA = phon[(wg * NSV + sA) * TPn + t];
        const int tokB = phon[(wg * NSV + sB) * TPn + t];

        f32x4 acc[4];
#pragma unroll
        for (int ii = 0; ii < 4; ++ii) acc[ii] = (f32x4){0.f, 0.f, 0.f, 0.f};
#pragma unroll
        for (int q = 0; q < 8; ++q) {
            bf16x8 bf = *(const bf16x8*)&hBf[q * 64 + l];
            acc[0] = __builtin_amdgcn_mfma_f32_16x16x32_bf16(
                resW[(wv * 8 + q) * 64 + l], bf, acc[0], 0, 0, 0);
#pragma unroll
            for (int ii = 1; ii < 4; ++ii) {
                acc[ii] = __builtin_amdgcn_mfma_f32_16x16x32_bf16(
                    AWw[ii * 512 + q * 64], bf, acc[ii], 0, 0, 0);
            }
        }
        const float4 pA = Ptu[tokA * Hn + u];   // in flight during C-write
        const float4 pB = Ptu[tokB * Hn + u];
        if (c16 < 8) {   // C: col=lane&15 (seq), row=(lane>>4)*4+reg [m89-verified]
#pragma unroll
            for (int ii = 0; ii < 4; ++ii) {
                int Rb = (4 * wv + ii) * 16 + rg * 4;
#pragma unroll
                for (int r = 0; r < 4; ++r)
                    gactG[(Rb + r) * 8 + c16] = (unsigned short)bf16rne(acc[ii][r]);
            }
        }
        __syncthreads();   // bar1: gactG visible; hBf reads done

        float g0A = bfu(gactG[(u) * 8 + sA]),         g0B = bfu(gactG[(u) * 8 + sB]);
        float g1A = bfu(gactG[(256 + u) * 8 + sA]),   g1B = bfu(gactG[(256 + u) * 8 + sB]);
        float g2A = bfu(gactG[(512 + u) * 8 + sA]),   g2B = bfu(gactG[(512 + u) * 8 + sB]);
        float g3A = bfu(gactG[(768 + u) * 8 + sA]),   g3B = bfu(gactG[(768 + u) * 8 + sB]);
        float hvA, hvB;
        {
            float gi = sigf(g0A + pA.x), gf = sigf(g1A + pA.y);
            float gg = tanh_fast(g2A + pA.z), go = sigf(g3A + pA.w);
            cA = fmaf(gf, cA, gi * gg); hvA = go * tanh_fast(cA);
        }
        {
            float gi = sigf(g0B + pB.x), gf = sigf(g1B + pB.y);
            float gg = tanh_fast(g2B + pB.z), go = sigf(g3B + pB.w);
            cB = fmaf(gf, cB, gi * gg); hvB = go * tanh_fast(cB);
        }
        if (t == lenA - 1) __builtin_nontemporal_store(hvA, &h0dec[(wg * NSV + sA) * Hn + u]);
        if (t == lenB - 1) __builtin_nontemporal_store(hvB, &h0dec[(wg * NSV + sB) * Hn + u]);
        {   // new h into B-fragment layout (k=u -> q=u>>5, g=(u>>3)&3, j=u&7)
            unsigned short* hb16 = (unsigned short*)hBf;
            int q = u >> 5, g = (u >> 3) & 3, j = u & 7;
            hb16[(q * 64 + g * 16 + sA) * 8 + j] = (unsigned short)bf16rne(hvA);
            hb16[(q * 64 + g * 16 + sB) * 8 + j] = (unsigned short)bf16rne(hvB);
        }
        __syncthreads();   // bar2: new h fragments visible
    }
}

// ---------------- decoder (R12 verbatim -- measured 453 us) ----------------
// M = 1280 fused; wave owns 5 M-tiles; 3 barriers/iter; RESQ_D=6; f32 gact.
__global__ KATTR void dec_kernel(
    const bf16x8* __restrict__ AW, const float4* __restrict__ Ptu,
    const float* __restrict__ fcb, const float* __restrict__ h0dec,
    const int* __restrict__ sosp, float* __restrict__ out) {
    const int tid = threadIdx.x, wg = blockIdx.x;
    const int wv = tid >> 6, l = tid & 63;
    const int c16 = l & 15, rg = l >> 4;
    const int u = tid >> 2, ch = tid & 3;
    const int sA = 2 * ch, sB = 2 * ch + 1;
    const int ln = tid & 63;
    __shared__ __align__(16) bf16x8 resW[16 * RESQ_D * 64];   // 98,304 B
    __shared__ __align__(16) uint4 hBf[8 * 64];               // 8,192 B
    __shared__ float gact[1280 * GSTR];                       // 46,080 B
    __shared__ float scx[NSV * SROW];                         // 8,320 B
    __shared__ unsigned long long gmax[2][NSV];               // 128 B -> 161,024 total

    if (tid < 512) {   // stage h0 into B-fragment layout
        int q = tid >> 6, ll = tid & 63, c = ll & 15, g = ll >> 4;
        uint4 v = make_uint4(0u, 0u, 0u, 0u);
        if (c < 8) {
            const float* hp = h0dec + (wg * NSV + c) * Hn + 32 * q + 8 * g;
            float4 v0 = *(const float4*)hp;
            float4 v1 = *(const float4*)(hp + 4);
            v = make_uint4(pk2(v0.x, v0.y), pk2(v0.z, v0.w), pk2(v1.x, v1.y), pk2(v1.z, v1.w));
        }
        hBf[tid] = v;
    }
    if (tid < 2 * NSV) ((unsigned long long*)gmax)[tid] = 0ull;
#pragma unroll
    for (int q = 0; q < RESQ_D; ++q)   // wave-private resident copy of tile0 q<6
        resW[(wv * RESQ_D + q) * 64 + l] = AW[((5 * wv) * 8 + q) * 64 + l];
    const int sos0 = sosp[0];
    const float fb = fcb[u];
    float cA = 0.f, cB = 0.f;
    __syncthreads();

    const bf16x8* AWw = AW + (5 * wv) * 512 + l;   // wave's first tile, this lane

    for (int i = 0; i <= TPn; ++i) {
        const bool full = (i < TPn);

        f32x4 acc[5];
#pragma unroll
        for (int ii = 0; ii < 5; ++ii) acc[ii] = (f32x4){0.f, 0.f, 0.f, 0.f};
#pragma unroll
        for (int q = 0; q < 8; ++q) {
            bf16x8 bf = *(const bf16x8*)&hBf[q * 64 + l];
            bf16x8 a0 = (q < RESQ_D) ? resW[(wv * RESQ_D + q) * 64 + l]
                                     : AWw[q * 64];
            acc[0] = __builtin_amdgcn_mfma_f32_16x16x32_bf16(a0, bf, acc[0], 0, 0, 0);
#pragma unroll
            for (int ii = 1; ii < 5; ++ii) {
                acc[ii] = __builtin_amdgcn_mfma_f32_16x16x32_bf16(
                    AWw[ii * 512 + q * 64], bf, acc[ii], 0, 0, 0);
            }
        }
        if (c16 < 8) {
#pragma unroll
            for (int ii = 0; ii < 5; ++ii) {
                int Rb = (5 * wv + ii) * 16 + rg * 4;
#pragma unroll
                for (int r = 0; r < 4; ++r) gact[(Rb + r) * GSTR + c16] = acc[ii][r];
            }
        }
        __syncthreads();   // bar1: gact visible; hBf reads done

        float g0A = 0.f, g1A = 0.f, g2A = 0.f, g3A = 0.f;
        float g0B = 0.f, g1B = 0.f, g2B = 0.f, g3B = 0.f;
        if (full) {
            g0A = gact[(u) * GSTR + sA];       g0B = gact[(u) * GSTR + sB];
            g1A = gact[(256 + u) * GSTR + sA]; g1B = gact[(256 + u) * GSTR + sB];
            g2A = gact[(512 + u) * GSTR + sA]; g2B = gact[(512 + u) * GSTR + sB];
            g3A = gact[(768 + u) * GSTR + sA]; g3B = gact[(768 + u) * GSTR + sB];
        }
        if (i > 0) {   // scores_{i-1} for v=u, seqs sA,sB (fc rows 1024+v)
            float scA = gact[(1024 + u) * GSTR + sA] + fb;
            float scB = gact[(1024 + u) * GSTR + sB] + fb;
            scx[sA * SROW + u] = scA;
            scx[sB * SROW + u] = scB;
            unsigned long long kA = amax_key(scA, u);
            unsigned long long kB = amax_key(scB, u);
#pragma unroll
            for (int off = 4; off < 64; off <<= 1) {
                unsigned long long oA = __shfl_xor(kA, off, 64);
                unsigned long long oB = __shfl_xor(kB, off, 64);
                if (oA > kA) kA = oA;
                if (oB > kB) kB = oB;
            }
            if (ln < 4) {
                atomicMax(&gmax[i & 1][sA], kA);
                atomicMax(&gmax[i & 1][sB], kB);
            }
        }
        __syncthreads();   // bar2: scx + gmax visible; gact reads done

        int tokA = sos0, tokB = sos0;
        if (i > 0) {
            {   // coalesced nt store of scores_{i-1}
                int s = tid >> 7, k = (tid & 127) * 2;
                f32x2 v = *(const f32x2*)&scx[s * SROW + k];
                __builtin_nontemporal_store(
                    v, (f32x2*)&out[((long)(wg * NSV + s) * TPn + (i - 1)) * Vn + k]);
            }
            tokA = (Vn - 1) - (int)(gmax[i & 1][sA] & 0xffffffffu);
            tokB = (Vn - 1) - (int)(gmax[i & 1][sB] & 0xffffffffu);
            if (tid < NSV) gmax[(i + 1) & 1][tid] = 0ull;   // reset other parity slot
        }

        if (full) {
            const float4 pA = Ptu[tokA * Hn + u];
            const float4 pB = Ptu[tokB * Hn + u];
            float hvA, hvB;
            {
                float gi = sigf(g0A + pA.x), gf = sigf(g1A + pA.y);
                float gg = tanh_fast(g2A + pA.z), go = sigf(g3A + pA.w);
                cA = fmaf(gf, cA, gi * gg); hvA = go * tanh_fast(cA);
            }
            {
                float gi = sigf(g0B + pB.x), gf = sigf(g1B + pB.y);
                float gg = tanh_fast(g2B + pB.z), go = sigf(g3B + pB.w);
                cB = fmaf(gf, cB, gi * gg); hvB = go * tanh_fast(cB);
            }
            unsigned short* hb16 = (unsigned short*)hBf;
            int q = u >> 5, g = (u >> 3) & 3, j = u & 7;
            hb16[(q * 64 + g * 16 + sA) * 8 + j] = (unsigned short)bf16rne(hvA);
            hb16[(q * 64 + g * 16 + sB) * 8 + j] = (unsigned short)bf16rne(hvB);
        }
        __syncthreads();   // bar3: new h fragments + gmax reset visible
    }
}

// ---------------- launch ----------------
extern "C" void kernel_launch(void* const* d_in, const int* in_sizes, int n_in,
                              void* d_out, int out_size, void* d_ws, size_t ws_size,
                              hipStream_t stream) {
    const int*   phon = (const int*)d_in[0];
    const int*   lens = (const int*)d_in[1];
    const float* emb  = (const float*)d_in[2];
    const float* eWih = (const float*)d_in[3];
    const float* eWhh = (const float*)d_in[4];
    const float* ebih = (const float*)d_in[5];
    const float* ebhh = (const float*)d_in[6];
    const float* dWih = (const float*)d_in[7];
    const float* dWhh = (const float*)d_in[8];
    const float* dbih = (const float*)d_in[9];
    const float* dbhh = (const float*)d_in[10];
    const float* fcW  = (const float*)d_in[11];
    const float* fcb  = (const float*)d_in[12];
    const int*   sos  = (const int*)d_in[13];
    float* out = (float*)d_out;

    float4* Ptu_e = (float4*)d_ws;            // 1 MB
    float4* Ptu_d = Ptu_e + 65536;            // 1 MB
    uint4*  AW_e  = (uint4*)(Ptu_d + 65536);  // 512 KB
    uint4*  AW_d  = AW_e + 32768;             // 640 KB
    float*  h0d   = (float*)(AW_d + 40960);   // 2 MB

    make_ptab<<<256, 256, 0, stream>>>(Ptu_e, emb, eWih, ebih, ebhh);
    make_ptab<<<256, 256, 0, stream>>>(Ptu_d, emb, dWih, dbih, dbhh);
    pack_afrag<<<128, 256, 0, stream>>>(AW_e, eWhh, eWhh, 64);   // fcW unused (ntile=64)
    pack_afrag<<<160, 256, 0, stream>>>(AW_d, dWhh, fcW, 80);
    enc_kernel<<<NWG, NT, 0, stream>>>((const bf16x8*)AW_e, Ptu_e, phon, lens, h0d);
    dec_kernel<<<NWG, NT, 0, stream>>>((const bf16x8*)AW_d, Ptu_d, fcb, h0d, sos, out);
}